// Round 3
// baseline (25.481 us; speedup 1.0000x reference)
//
#include <hip/hip_runtime.h>
#include <math.h>

#define LL 50
#define DD 50
#define RR 3
#define CC 10
#define PC_ROWS 256          // vocab rows per precompute block
#define PC_STRIDE 51         // padded LDS row stride (floats): 51%32=19 -> conflict-free

// Kernel 1: dtab[v] = (dot(row_v, w0), dot(row_v, w1), dot(row_v, w2), 0)
// Coalesced: block stages 256 rows (51.2 KB) into LDS via float2, padded stride.
__global__ __launch_bounds__(256) void precompute_dots_kernel(
    const float* __restrict__ emb_table,  // [VOCAB, D]
    const float* __restrict__ W,          // [R*D] = [150]
    float4*      __restrict__ dtab,       // [VOCAB]
    int vocab)
{
    __shared__ float s[PC_ROWS * PC_STRIDE];
    __shared__ float sW[RR * DD];

    const int tid  = threadIdx.x;
    const int base = blockIdx.x * PC_ROWS;
    const int rows = min(PC_ROWS, vocab - base);

    if (tid < RR * DD) sW[tid] = W[tid];

    // Stage rows*25 float2 elements, coalesced (512B per wave per instr).
    const float2* src = (const float2*)(emb_table + (size_t)base * DD); // 8B-aligned
    if (rows == PC_ROWS) {
        #pragma unroll
        for (int k = 0; k < PC_ROWS * 25 / 256; ++k) {   // 25 iters
            int i = k * 256 + tid;
            float2 v = src[i];
            int r = i / 25, c = i - r * 25;
            s[r * PC_STRIDE + 2 * c]     = v.x;
            s[r * PC_STRIDE + 2 * c + 1] = v.y;
        }
    } else {
        for (int i = tid; i < rows * 25; i += 256) {
            float2 v = src[i];
            int r = i / 25, c = i - r * 25;
            s[r * PC_STRIDE + 2 * c]     = v.x;
            s[r * PC_STRIDE + 2 * c + 1] = v.y;
        }
    }
    __syncthreads();

    if (tid < rows) {
        const float* row = s + tid * PC_STRIDE;
        float d0 = 0.f, d1 = 0.f, d2 = 0.f;
        #pragma unroll
        for (int j = 0; j < DD; ++j) {
            float e = row[j];                  // conflict-free (stride 51)
            d0 = fmaf(e, sW[j],          d0);  // sW[j] wave-uniform -> broadcast
            d1 = fmaf(e, sW[DD + j],     d1);
            d2 = fmaf(e, sW[2 * DD + j], d2);
        }
        dtab[base + tid] = make_float4(d0, d1, d2, 0.f);
    }
}

// Kernel 2: one wave per sample; pure intra-wave shuffles, no LDS, no barriers.
__global__ __launch_bounds__(256) void fused_combo_kernel(
    const int*    __restrict__ x,          // [B, L]
    const float*  __restrict__ emb_mask,   // [B, L]
    const int*    __restrict__ combo_idx,  // [B, C, R], values in [0, L)
    const float4* __restrict__ dtab,       // [VOCAB]
    const float*  __restrict__ bvec,       // [1]
    float*        __restrict__ out,        // [B]
    int B)
{
    const int tid  = threadIdx.x;
    const int w    = tid >> 6;
    const int lane = tid & 63;
    const int b    = blockIdx.x * 4 + w;
    if (b >= B) return;                    // wave-uniform

    // Lane l (<50) holds masked dots for position l of this sample.
    float d0 = 0.f, d1 = 0.f, d2 = 0.f;
    if (lane < LL) {
        int   row = x[b * LL + lane];
        float m   = emb_mask[b * LL + lane];
        float4 d  = dtab[row];             // 16B gather, 1.6MB L2-resident table
        d0 = d.x * m; d1 = d.y * m; d2 = d.z * m;
    }

    // Lanes <30 hold the combo indices; redistribute so lane c (<10) gets its 3.
    int ci = 0;
    if (lane < CC * RR) ci = combo_idx[b * (CC * RR) + lane];
    int i0 = __shfl(ci, 3 * lane    ) & 63;
    int i1 = __shfl(ci, 3 * lane + 1) & 63;
    int i2 = __shfl(ci, 3 * lane + 2) & 63;

    // Cross-lane gather of the d-values, then sigmoid on lanes <10.
    float sacc = __shfl(d0, i0) + __shfl(d1, i1) + __shfl(d2, i2) + bvec[0];
    float v = (lane < CC) ? 1.0f / (1.0f + __expf(-sacc)) : 0.f;

    // Sum lanes 0..9 (zeros elsewhere within reach of offset-8 tree).
    v += __shfl_down(v, 8);
    v += __shfl_down(v, 4);
    v += __shfl_down(v, 2);
    v += __shfl_down(v, 1);
    if (lane == 0) out[b] = v;
}

extern "C" void kernel_launch(void* const* d_in, const int* in_sizes, int n_in,
                              void* d_out, int out_size, void* d_ws, size_t ws_size,
                              hipStream_t stream) {
    const int*   x         = (const int*)d_in[0];
    const float* emb_mask  = (const float*)d_in[1];
    const int*   combo_idx = (const int*)d_in[2];
    // d_in[3] = step (unused)
    const float* emb_table = (const float*)d_in[4];
    const float* W         = (const float*)d_in[5];
    const float* bvec      = (const float*)d_in[6];
    float*       out       = (float*)d_out;

    const int B     = out_size;            // OUT == 1
    const int vocab = in_sizes[4] / DD;    // emb_table is [VOCAB, D]

    float4* dtab = (float4*)d_ws;          // 16 * VOCAB = 1.6 MB scratch

    precompute_dots_kernel<<<(vocab + PC_ROWS - 1) / PC_ROWS, 256, 0, stream>>>(
        emb_table, W, dtab, vocab);

    fused_combo_kernel<<<(B + 3) / 4, 256, 0, stream>>>(
        x, emb_mask, combo_idx, dtab, bvec, out, B);
}